// Round 7
// baseline (4168.209 us; speedup 1.0000x reference)
//
#include <hip/hip_runtime.h>

#define D_FEAT 64
#define BSHIFT 7                  // 128 nodes per bucket
#define BNODES 128
#define CHUNK 4096
#define SCAP 6144                 // srcsort LDS staging cap (records); mean bucket cnt ~4092

typedef unsigned int uint;
typedef unsigned short ushort;

static __device__ __forceinline__ ushort f2bf(float f) {
    uint u = __float_as_uint(f);
    uint r = (u + 0x7fffu + ((u >> 16) & 1u)) >> 16;   // RNE
    return (ushort)r;
}
static __device__ __forceinline__ float bf2f(ushort b) {
    return __uint_as_float(((uint)b) << 16);
}

// ---------- Phase A: bucket histogram (bucket = dst >> 7) ----------
__global__ __launch_bounds__(256) void bucket_hist(const int* __restrict__ dst,
                                                   int* __restrict__ bcount,
                                                   int n_edges, int nbuck) {
    __shared__ int h[1024];
    for (int i = threadIdx.x; i < nbuck; i += 256) h[i] = 0;
    __syncthreads();
    for (int e = blockIdx.x * blockDim.x + threadIdx.x; e < n_edges; e += gridDim.x * blockDim.x)
        atomicAdd(&h[dst[e] >> BSHIFT], 1);
    __syncthreads();
    for (int i = threadIdx.x; i < nbuck; i += 256)
        if (h[i]) atomicAdd(&bcount[i], h[i]);
}

// ---------- Phase B: blocked exclusive scan over nbuck counts ----------
__global__ __launch_bounds__(256) void bucket_scan(const int* __restrict__ bcount,
                                                   int* __restrict__ bbase,
                                                   int* __restrict__ bcursor, int nbuck) {
    __shared__ int ssum[256];
    int t = threadIdx.x;
    int loc[4]; int s = 0;
    for (int k = 0; k < 4; ++k) { int b = t*4+k; int v = (b < nbuck) ? bcount[b] : 0; loc[k] = s; s += v; }
    ssum[t] = s;
    __syncthreads();
    for (int off = 1; off < 256; off <<= 1) {
        int u = (t >= off) ? ssum[t-off] : 0; __syncthreads(); ssum[t] += u; __syncthreads();
    }
    int excl = ssum[t] - s;
    for (int k = 0; k < 4; ++k) {
        int b = t*4+k;
        if (b < nbuck) { bbase[b] = excl + loc[k]; bcursor[b] = excl + loc[k]; }
    }
}

// ---------- Phase C: per-chunk counting sort by bucket, flush to inter ----------
__global__ __launch_bounds__(256) void partition_kernel(
        const int* __restrict__ src, const int* __restrict__ dst,
        const float* __restrict__ w, int* __restrict__ bcursor,
        int2* __restrict__ inter, int n_edges, int nbuck) {
    __shared__ int hist[1024], lofs[1024], cur[1024], gbase[1024];
    __shared__ int2 buf[CHUNK];
    __shared__ ushort bb[CHUNK];
    __shared__ int ssum[256];
    int t = threadIdx.x;
    int beg = blockIdx.x * CHUNK;
    int end = min(beg + CHUNK, n_edges);
    int cnt = end - beg;

    for (int i = t; i < nbuck; i += 256) hist[i] = 0;
    __syncthreads();
    for (int i = beg + t; i < end; i += 256)
        atomicAdd(&hist[dst[i] >> BSHIFT], 1);
    __syncthreads();
    // blocked exclusive scan hist -> lofs
    int loc[4]; int s = 0;
    for (int k = 0; k < 4; ++k) { int b = t*4+k; int v = (b < nbuck) ? hist[b] : 0; loc[k] = s; s += v; }
    ssum[t] = s;
    __syncthreads();
    for (int off = 1; off < 256; off <<= 1) {
        int u = (t >= off) ? ssum[t-off] : 0; __syncthreads(); ssum[t] += u; __syncthreads();
    }
    int excl = ssum[t] - s;
    for (int k = 0; k < 4; ++k) {
        int b = t*4+k;
        if (b < nbuck) { lofs[b] = excl + loc[k]; cur[b] = excl + loc[k]; }
    }
    __syncthreads();
    // scatter into LDS, bucket-ordered; record bucket id per slot
    for (int i = beg + t; i < end; i += 256) {
        int d = dst[i];
        int b = d >> BSHIFT;
        int p = atomicAdd(&cur[b], 1);
        buf[p] = make_int2((src[i] << BSHIFT) | (d & (BNODES-1)), __float_as_int(w[i]));
        bb[p] = (ushort)b;
    }
    __syncthreads();
    // reserve global ranges
    for (int k = 0; k < 4; ++k) {
        int b = t*4+k;
        if (b < nbuck && hist[b]) gbase[b] = atomicAdd(&bcursor[b], hist[b]);
    }
    __syncthreads();
    // direct per-edge flush (staged buf is bucket-sorted -> mostly contiguous)
    for (int i = t; i < cnt; i += 256) {
        int b = bb[i];
        inter[gbase[b] + (i - lofs[b])] = buf[i];
    }
}

// ---------- Phase D: per-bucket counting sort by src>>9 (ascending-src stream) ----------
// key = (src<<7)|dstlo, so key>>16 == src>>9 exactly (dstlo<128 cannot carry).
__global__ __launch_bounds__(256) void srcsort_kernel(
        const int2* __restrict__ inter, const int* __restrict__ bbase,
        const int* __restrict__ bcount, int2* __restrict__ recw) {
    __shared__ int2 sbuf[SCAP];
    __shared__ int hist[256], cur[256];
    int bkt = blockIdx.x;
    int t = threadIdx.x;
    int base = bbase[bkt];
    int cnt  = bcount[bkt];
    if (cnt <= SCAP) {
        for (int i = t; i < cnt; i += 256) sbuf[i] = inter[base + i];
        hist[t] = 0;
        __syncthreads();
        for (int i = t; i < cnt; i += 256)
            atomicAdd(&hist[sbuf[i].x >> 16], 1);
        __syncthreads();
        int v = hist[t]; cur[t] = v;
        __syncthreads();
        for (int off = 1; off < 256; off <<= 1) {
            int u = (t >= off) ? cur[t-off] : 0; __syncthreads(); cur[t] += u; __syncthreads();
        }
        int excl = cur[t] - v;
        __syncthreads();
        cur[t] = excl;
        __syncthreads();
        for (int i = t; i < cnt; i += 256) {
            int2 r = sbuf[i];
            int p = atomicAdd(&cur[r.x >> 16], 1);
            recw[base + p] = r;
        }
    } else {
        // overflow fallback: copy unsorted (correct, loses locality for this bucket)
        for (int i = t; i < cnt; i += 256) recw[base + i] = inter[base + i];
    }
}

// ---------- convert: f32 features -> bf16, vectorized ----------
__global__ void cvt_bf16(const float* __restrict__ in, ushort* __restrict__ out, int n4) {
    int i = blockIdx.x * blockDim.x + threadIdx.x;
    int stride = gridDim.x * blockDim.x;
    for (; i < n4; i += stride) {
        float4 v = ((const float4*)in)[i];
        ushort4 o;
        o.x = f2bf(v.x); o.y = f2bf(v.y); o.z = f2bf(v.z); o.w = f2bf(v.w);
        ((ushort4*)out)[i] = o;
    }
}

// ---------- gather: one WG per 128-node bucket; LDS f32 accumulators ----------
// Edges within bucket are ascending in src>>9 -> near-sequential row stream.
template <bool OUT_BF16>
__global__ __launch_bounds__(256) void bucket_gather(
        const ushort* __restrict__ h, const int2* __restrict__ recw,
        const int* __restrict__ bbase, const int* __restrict__ bcount,
        void* __restrict__ out_v, int n_nodes) {
    __shared__ float acc[BNODES * D_FEAT];   // 32 KB
    int t = threadIdx.x;
    int bkt = blockIdx.x;
    for (int i = t; i < BNODES * D_FEAT; i += 256) acc[i] = 0.f;
    int base = __builtin_amdgcn_readfirstlane(bbase[bkt]);
    int cnt  = __builtin_amdgcn_readfirstlane(bcount[bkt]);
    __syncthreads();

    int wid = t >> 6, f = t & 63;
    int per = (cnt + 3) >> 2;                 // split among 4 waves, contiguous (keeps order)
    int jb = base + wid * per;
    int je = min(jb + per, base + cnt);
    int j = jb;
    for (; j + 8 <= je; j += 8) {
        #pragma unroll
        for (int k = 0; k < 8; ++k) {
            int2 r = recw[j + k];                                   // uniform -> scalar load
            float hv = bf2f(h[((size_t)(r.x >> BSHIFT) << 6) + f]); // 2B/lane row read
            atomicAdd(&acc[((r.x & (BNODES-1)) << 6) + f], __int_as_float(r.y) * hv);
        }
    }
    for (; j < je; ++j) {
        int2 r = recw[j];
        float hv = bf2f(h[((size_t)(r.x >> BSHIFT) << 6) + f]);
        atomicAdd(&acc[((r.x & (BNODES-1)) << 6) + f], __int_as_float(r.y) * hv);
    }
    __syncthreads();

    size_t nb64 = ((size_t)bkt << BSHIFT) << 6;
    int lim = min(BNODES * D_FEAT, (n_nodes - (bkt << BSHIFT)) * D_FEAT);
    if (OUT_BF16) {
        ushort* o = (ushort*)out_v;
        for (int i = t; i < lim; i += 256) o[nb64 + i] = f2bf(acc[i]);
    } else {
        float* o = (float*)out_v;
        for (int i = t; i < lim; i += 256) o[nb64 + i] = acc[i];
    }
}

extern "C" void kernel_launch(void* const* d_in, const int* in_sizes, int n_in,
                              void* d_out, int out_size, void* d_ws, size_t ws_size,
                              hipStream_t stream) {
    const float* x   = (const float*)d_in[0];
    const float* ew  = (const float*)d_in[1];
    const int*   src = (const int*)d_in[2];
    const int*   dst = (const int*)d_in[3];
    float* out = (float*)d_out;

    const int n_nodes = in_sizes[0] / D_FEAT;              // 100000
    const int n_edges = in_sizes[1];                       // 3200000
    const int nbuck   = (n_nodes + BNODES - 1) >> BSHIFT;  // 782
    const int n_feat_total = n_nodes * D_FEAT;

    const size_t ed8_bytes = (size_t)n_edges * 8;          // 25.6 MB
    const size_t bf_bytes  = (size_t)n_feat_total * 2;     // 12.8 MB

    // workspace: [region0: inter(25.6MB) -> later x_bf(12.8)+buf1(12.8)]
    //            [recw 25.6MB][bcount][bbase][bcursor]
    char* ws = (char*)d_ws;
    int2*   inter = (int2*)ws;
    ushort* x_bf  = (ushort*)ws;
    ushort* buf1  = (ushort*)(ws + bf_bytes);
    ws += (ed8_bytes > 2 * bf_bytes ? ed8_bytes : 2 * bf_bytes);
    int2* recw    = (int2*)ws;                ws += ed8_bytes;
    int*  bcount  = (int*)ws;                 ws += 1024 * 4;
    int*  bbase   = (int*)ws;                 ws += 1024 * 4;
    int*  bcursor = (int*)ws;

    // --- build: dst-bucketed, src-sorted edge stream ---
    hipMemsetAsync(bcount, 0, 1024 * 4, stream);
    bucket_hist<<<256, 256, 0, stream>>>(dst, bcount, n_edges, nbuck);
    bucket_scan<<<1, 256, 0, stream>>>(bcount, bbase, bcursor, nbuck);
    partition_kernel<<<(n_edges + CHUNK - 1) / CHUNK, 256, 0, stream>>>(
        src, dst, ew, bcursor, inter, n_edges, nbuck);
    srcsort_kernel<<<nbuck, 256, 0, stream>>>(inter, bbase, bcount, recw);

    // --- convert x to bf16 (inter region now free) ---
    cvt_bf16<<<1024, 256, 0, stream>>>(x, x_bf, n_feat_total / 4);

    // --- 3 gather hops: x_bf -> buf1 -> x_bf -> out(f32) ---
    bucket_gather<true ><<<nbuck, 256, 0, stream>>>(x_bf, recw, bbase, bcount, buf1, n_nodes);
    bucket_gather<true ><<<nbuck, 256, 0, stream>>>(buf1, recw, bbase, bcount, x_bf, n_nodes);
    bucket_gather<false><<<nbuck, 256, 0, stream>>>(x_bf, recw, bbase, bcount, out,  n_nodes);
}

// Round 8
// 445.534 us; speedup vs baseline: 9.3555x; 9.3555x over previous
//
#include <hip/hip_runtime.h>

#define D_FEAT 64
#define CHUNK 8192
#define BSHIFT 9
#define BSIZE 512

typedef unsigned int uint;
typedef unsigned short ushort;

static __device__ __forceinline__ ushort f2bf(float f) {
    uint u = __float_as_uint(f);
    uint r = (u + 0x7fffu + ((u >> 16) & 1u)) >> 16;   // RNE
    return (ushort)r;
}
static __device__ __forceinline__ float bf2f(ushort b) {
    return __uint_as_float(((uint)b) << 16);
}

// ---------- Phase A: bucket histogram (bucket = dst >> 9) ----------
__global__ void bucket_hist(const int* __restrict__ dst, int* __restrict__ bcount, int n_edges) {
    __shared__ int h[256];
    h[threadIdx.x] = 0;
    __syncthreads();
    for (int e = blockIdx.x * blockDim.x + threadIdx.x; e < n_edges; e += gridDim.x * blockDim.x)
        atomicAdd(&h[dst[e] >> BSHIFT], 1);
    __syncthreads();
    int v = h[threadIdx.x];
    if (v) atomicAdd(&bcount[threadIdx.x], v);
}

// ---------- Phase B: scan 256 bucket counts -> bbase, bcursor ----------
__global__ void bucket_scan(const int* __restrict__ bcount, int* __restrict__ bbase,
                            int* __restrict__ bcursor) {
    __shared__ int s[256];
    int t = threadIdx.x;
    int v = bcount[t];
    s[t] = v;
    __syncthreads();
    for (int off = 1; off < 256; off <<= 1) {
        int u = (t >= off) ? s[t - off] : 0;
        __syncthreads();
        s[t] += u;
        __syncthreads();
    }
    int excl = s[t] - v;
    bbase[t] = excl;
    bcursor[t] = excl;
}

// ---------- Phase C: per-chunk counting sort by bucket, contiguous flush ----------
__global__ __launch_bounds__(256) void partition_kernel(
        const int* __restrict__ src, const int* __restrict__ dst,
        const float* __restrict__ w, int* __restrict__ bcursor,
        int2* __restrict__ inter, int n_edges) {
    __shared__ int hist[256];
    __shared__ int lofs[256];
    __shared__ int cur[256];
    __shared__ int gbase[256];
    __shared__ int2 buf[CHUNK];          // 64 KB staging
    int t = threadIdx.x;
    int beg = blockIdx.x * CHUNK;
    int end = min(beg + CHUNK, n_edges);

    hist[t] = 0;
    __syncthreads();
    for (int i = beg + t; i < end; i += 256)
        atomicAdd(&hist[dst[i] >> BSHIFT], 1);
    __syncthreads();
    int v = hist[t];
    lofs[t] = v;
    __syncthreads();
    for (int off = 1; off < 256; off <<= 1) {
        int u = (t >= off) ? lofs[t - off] : 0;
        __syncthreads();
        lofs[t] += u;
        __syncthreads();
    }
    int excl = lofs[t] - v;
    __syncthreads();
    lofs[t] = excl;
    cur[t]  = excl;
    __syncthreads();
    for (int i = beg + t; i < end; i += 256) {
        int d = dst[i];
        int b = d >> BSHIFT;
        int p = atomicAdd(&cur[b], 1);
        buf[p] = make_int2((src[i] << BSHIFT) | (d & (BSIZE - 1)), __float_as_int(w[i]));
    }
    __syncthreads();
    if (hist[t]) gbase[t] = atomicAdd(&bcursor[t], hist[t]);
    __syncthreads();
    int wid = t >> 6, lane = t & 63;
    for (int b = wid; b < 256; b += 4) {
        int c = hist[b];
        if (!c) continue;
        int lo = lofs[b], gb = gbase[b];
        for (int k = lane; k < c; k += 64)
            inter[gb + k] = buf[lo + k];
    }
}

// ---------- Phase D: per-bucket counting sort by node; emits row_ptr + packed 4B edges ----------
// packed edge: (src << 15) | wq15, w ≈ (wq + 0.5) / 32768
__global__ __launch_bounds__(512) void finalize_kernel(
        const int2* __restrict__ inter, const int* __restrict__ bbase,
        const int* __restrict__ bcount, uint* __restrict__ edges,
        int* __restrict__ row_ptr, int n_nodes, int n_edges) {
    __shared__ int hist[BSIZE];
    __shared__ int cur[BSIZE];
    int b = blockIdx.x;
    int t = threadIdx.x;
    int base = bbase[b];
    int cnt  = bcount[b];

    hist[t] = 0;
    __syncthreads();
    for (int i = t; i < cnt; i += BSIZE)
        atomicAdd(&hist[inter[base + i].x & (BSIZE - 1)], 1);
    __syncthreads();
    int v = hist[t];
    cur[t] = v;
    __syncthreads();
    for (int off = 1; off < BSIZE; off <<= 1) {
        int u = (t >= off) ? cur[t - off] : 0;
        __syncthreads();
        cur[t] += u;
        __syncthreads();
    }
    int excl = cur[t] - v;
    int node = (b << BSHIFT) + t;
    if (node < n_nodes) row_ptr[node] = base + excl;
    if (b == 0 && t == 0) row_ptr[n_nodes] = n_edges;
    __syncthreads();
    cur[t] = excl;
    __syncthreads();
    for (int i = t; i < cnt; i += BSIZE) {
        int2 r = inter[base + i];
        int dlo = r.x & (BSIZE - 1);
        int p = atomicAdd(&cur[dlo], 1);
        float wf = __int_as_float(r.y);
        uint wq = (uint)(wf * 32768.0f);
        if (wq > 32767u) wq = 32767u;
        edges[base + p] = ((uint)(r.x >> BSHIFT) << 15) | wq;
    }
}

// ---------- convert: f32 features -> bf16, vectorized ----------
__global__ void cvt_bf16(const float* __restrict__ in, ushort* __restrict__ out, int n4) {
    int i = blockIdx.x * blockDim.x + threadIdx.x;
    int stride = gridDim.x * blockDim.x;
    for (; i < n4; i += stride) {
        float4 v = ((const float4*)in)[i];
        ushort4 o;
        o.x = f2bf(v.x); o.y = f2bf(v.y); o.z = f2bf(v.z); o.w = f2bf(v.w);
        ((ushort4*)out)[i] = o;
    }
}

static __device__ __forceinline__ float wq2f(uint ev) {
    return (float)(ev & 32767u) * (1.0f / 32768.0f) + (1.0f / 65536.0f);
}

// ---------- gather hop, feature-split: wave = (node, feature-half) ----------
// fhalf = (blockIdx>>2)&1 so (with round-robin blockIdx->XCD) XCDs 0-3 touch
// only columns 0..31 of h and XCDs 4-7 only columns 32..63: per-XCD compulsory
// fetch and L2 working set both halve. 64 lanes = 2 edges x 32 features.
template <bool OUT_BF16>
__global__ __launch_bounds__(256) void gather_half(
        const ushort* __restrict__ h, const uint* __restrict__ edges,
        const int* __restrict__ row_ptr, void* __restrict__ out_v, int n_nodes) {
    uint wg = blockIdx.x;
    int fhalf = (int)((wg >> 2) & 1u);
    int q     = (int)(wg & 3u);
    int g     = (int)(wg >> 3);
    int node  = __builtin_amdgcn_readfirstlane((g * 4 + q) * 4 + (int)(threadIdx.x >> 6));
    if (node >= n_nodes) return;
    int lane = threadIdx.x & 63;
    int e2 = lane >> 5;                    // which edge of the pair
    int c  = lane & 31;                    // feature within half
    int fcol = (fhalf << 5) + c;           // column in the 64-wide row
    int beg = __builtin_amdgcn_readfirstlane(row_ptr[node]);
    int end = __builtin_amdgcn_readfirstlane(row_ptr[node + 1]);

    float acc = 0.0f;
    int j = beg;
    // head: align to even index so uint2 pair loads are 8B-aligned
    if ((j & 1) && j < end) {
        uint ev = edges[j];                                   // uniform -> scalar
        if (!e2) acc += wq2f(ev) * bf2f(h[((size_t)(ev >> 15) << 6) + fcol]);
        ++j;
    }
    // main: 16 edges (8 aligned pairs) per iteration, scalar pair loads
    for (; j + 16 <= end; j += 16) {
        #pragma unroll
        for (int k = 0; k < 8; ++k) {
            uint2 evp = ((const uint2*)(edges + j))[k];       // uniform -> s_load_dwordx2
            uint ev = e2 ? evp.y : evp.x;
            acc += wq2f(ev) * bf2f(h[((size_t)(ev >> 15) << 6) + fcol]);
        }
    }
    // pair tail
    for (; j + 2 <= end; j += 2) {
        uint2 evp = *(const uint2*)(edges + j);
        uint ev = e2 ? evp.y : evp.x;
        acc += wq2f(ev) * bf2f(h[((size_t)(ev >> 15) << 6) + fcol]);
    }
    // single tail
    if (j < end) {
        uint ev = edges[j];
        if (!e2) acc += wq2f(ev) * bf2f(h[((size_t)(ev >> 15) << 6) + fcol]);
    }

    acc += __shfl_xor(acc, 32);            // fold the two edge slots
    if (e2 == 0) {
        size_t o = ((size_t)node << 6) + fcol;
        if (OUT_BF16) ((ushort*)out_v)[o] = f2bf(acc);
        else          ((float*)out_v)[o]  = acc;
    }
}

extern "C" void kernel_launch(void* const* d_in, const int* in_sizes, int n_in,
                              void* d_out, int out_size, void* d_ws, size_t ws_size,
                              hipStream_t stream) {
    const float* x   = (const float*)d_in[0];
    const float* ew  = (const float*)d_in[1];
    const int*   src = (const int*)d_in[2];
    const int*   dst = (const int*)d_in[3];
    float* out = (float*)d_out;

    const int n_nodes = in_sizes[0] / D_FEAT;   // 100000
    const int n_edges = in_sizes[1];            // 3200000
    const int nbuck   = (n_nodes + BSIZE - 1) >> BSHIFT;   // 196
    const int n_feat_total = n_nodes * D_FEAT;

    const size_t ed8_bytes = (size_t)n_edges * 8;          // 25.6 MB (inter)
    const size_t ed4_bytes = (size_t)n_edges * 4;          // 12.8 MB (packed edges)
    const size_t bf_bytes  = (size_t)n_feat_total * 2;     // 12.8 MB

    // workspace: [region0: inter(25.6MB) -> later x_bf(12.8)+buf1(12.8)]
    //            [edges 12.8MB][row_ptr][bcount][bbase][bcursor]
    char* ws = (char*)d_ws;
    int2*   inter  = (int2*)ws;
    ushort* x_bf   = (ushort*)ws;
    ushort* buf1   = (ushort*)(ws + bf_bytes);
    ws += (ed8_bytes > 2 * bf_bytes ? ed8_bytes : 2 * bf_bytes);
    uint* edges    = (uint*)ws;                 ws += ed4_bytes;
    int*  row_ptr  = (int*)ws;                  ws += (size_t)(n_nodes + 1) * 4;
    int*  bcount   = (int*)ws;                  ws += 256 * 4;
    int*  bbase    = (int*)ws;                  ws += 256 * 4;
    int*  bcursor  = (int*)ws;

    // --- build dst-sorted CSR (bucketed counting sort); uses inter ---
    hipMemsetAsync(bcount, 0, 256 * 4, stream);
    bucket_hist<<<512, 256, 0, stream>>>(dst, bcount, n_edges);
    bucket_scan<<<1, 256, 0, stream>>>(bcount, bbase, bcursor);
    partition_kernel<<<(n_edges + CHUNK - 1) / CHUNK, 256, 0, stream>>>(
        src, dst, ew, bcursor, inter, n_edges);
    finalize_kernel<<<nbuck, BSIZE, 0, stream>>>(
        inter, bbase, bcount, edges, row_ptr, n_nodes, n_edges);

    // --- convert x to bf16 (inter region now free) ---
    cvt_bf16<<<1024, 256, 0, stream>>>(x, x_bf, n_feat_total / 4);

    // --- 3 gather hops, feature-split: x_bf -> buf1 -> x_bf -> out(f32) ---
    const int grd = ((n_nodes + 15) >> 4) * 8;   // (node-groups of 16) x 8 (4 quads x 2 halves)
    gather_half<true ><<<grd, 256, 0, stream>>>(x_bf, edges, row_ptr, buf1, n_nodes);
    gather_half<true ><<<grd, 256, 0, stream>>>(buf1, edges, row_ptr, x_bf, n_nodes);
    gather_half<false><<<grd, 256, 0, stream>>>(x_bf, edges, row_ptr, out,  n_nodes);
}

// Round 9
// 314.986 us; speedup vs baseline: 13.2330x; 1.4145x over previous
//
#include <hip/hip_runtime.h>

#define D_FEAT 64
#define CHUNK 4096
#define BSHIFT 9
#define BSIZE 512
#define NPW 8                      // nodes per wave in gather

typedef unsigned int uint;
typedef unsigned short ushort;
typedef unsigned char uchar;

static __device__ __forceinline__ ushort f2bf(float f) {
    uint u = __float_as_uint(f);
    uint r = (u + 0x7fffu + ((u >> 16) & 1u)) >> 16;   // RNE
    return (ushort)r;
}
static __device__ __forceinline__ float bf2f(ushort b) {
    return __uint_as_float(((uint)b) << 16);
}
static __device__ __forceinline__ float wq2f(uint ev) {
    return (float)(ev & 32767u) * (1.0f / 32768.0f) + (1.0f / 65536.0f);
}

// ---------- Phase A: bucket histogram (bucket = dst >> 9) ----------
__global__ void bucket_hist(const int* __restrict__ dst, int* __restrict__ bcount, int n_edges) {
    __shared__ int h[256];
    h[threadIdx.x] = 0;
    __syncthreads();
    for (int e = blockIdx.x * blockDim.x + threadIdx.x; e < n_edges; e += gridDim.x * blockDim.x)
        atomicAdd(&h[dst[e] >> BSHIFT], 1);
    __syncthreads();
    int v = h[threadIdx.x];
    if (v) atomicAdd(&bcount[threadIdx.x], v);
}

// ---------- Phase B: scan 256 bucket counts -> bbase, bcursor ----------
__global__ void bucket_scan(const int* __restrict__ bcount, int* __restrict__ bbase,
                            int* __restrict__ bcursor) {
    __shared__ int s[256];
    int t = threadIdx.x;
    int v = bcount[t];
    s[t] = v;
    __syncthreads();
    for (int off = 1; off < 256; off <<= 1) {
        int u = (t >= off) ? s[t - off] : 0;
        __syncthreads();
        s[t] += u;
        __syncthreads();
    }
    int excl = s[t] - v;
    bbase[t] = excl;
    bcursor[t] = excl;
}

// ---------- Phase C: per-chunk counting sort by bucket, per-edge flush ----------
__global__ __launch_bounds__(256) void partition_kernel(
        const int* __restrict__ src, const int* __restrict__ dst,
        const float* __restrict__ w, int* __restrict__ bcursor,
        int2* __restrict__ inter, int n_edges) {
    __shared__ int hist[256];
    __shared__ int lofs[256];
    __shared__ int cur[256];
    __shared__ int gbase[256];
    __shared__ int2 buf[CHUNK];          // 32 KB staging
    __shared__ uchar bb[CHUNK];          // 4 KB bucket ids
    int t = threadIdx.x;
    int beg = blockIdx.x * CHUNK;
    int end = min(beg + CHUNK, n_edges);
    int cnt = end - beg;

    hist[t] = 0;
    __syncthreads();
    for (int i = beg + t; i < end; i += 256)
        atomicAdd(&hist[dst[i] >> BSHIFT], 1);
    __syncthreads();
    int v = hist[t];
    lofs[t] = v;
    __syncthreads();
    for (int off = 1; off < 256; off <<= 1) {
        int u = (t >= off) ? lofs[t - off] : 0;
        __syncthreads();
        lofs[t] += u;
        __syncthreads();
    }
    int excl = lofs[t] - v;
    __syncthreads();
    lofs[t] = excl;
    cur[t]  = excl;
    __syncthreads();
    for (int i = beg + t; i < end; i += 256) {
        int d = dst[i];
        int b = d >> BSHIFT;
        int p = atomicAdd(&cur[b], 1);
        buf[p] = make_int2((src[i] << BSHIFT) | (d & (BSIZE - 1)), __float_as_int(w[i]));
        bb[p] = (uchar)b;
    }
    __syncthreads();
    if (hist[t]) gbase[t] = atomicAdd(&bcursor[t], hist[t]);
    __syncthreads();
    // per-edge flush: buf is bucket-sorted -> writes are near-contiguous runs
    for (int i = t; i < cnt; i += 256) {
        int b = bb[i];
        inter[gbase[b] + (i - lofs[b])] = buf[i];
    }
}

// ---------- Phase D: per-bucket counting sort by node; emits row_ptr + packed 4B edges ----------
// packed edge: (src << 15) | wq15, w ≈ (wq + 0.5) / 32768
__global__ __launch_bounds__(512) void finalize_kernel(
        const int2* __restrict__ inter, const int* __restrict__ bbase,
        const int* __restrict__ bcount, uint* __restrict__ edges,
        int* __restrict__ row_ptr, int n_nodes, int n_edges) {
    __shared__ int hist[BSIZE];
    __shared__ int cur[BSIZE];
    int b = blockIdx.x;
    int t = threadIdx.x;
    int base = bbase[b];
    int cnt  = bcount[b];

    hist[t] = 0;
    __syncthreads();
    for (int i = t; i < cnt; i += BSIZE)
        atomicAdd(&hist[inter[base + i].x & (BSIZE - 1)], 1);
    __syncthreads();
    int v = hist[t];
    cur[t] = v;
    __syncthreads();
    for (int off = 1; off < BSIZE; off <<= 1) {
        int u = (t >= off) ? cur[t - off] : 0;
        __syncthreads();
        cur[t] += u;
        __syncthreads();
    }
    int excl = cur[t] - v;
    int node = (b << BSHIFT) + t;
    if (node < n_nodes) row_ptr[node] = base + excl;
    if (b == 0 && t == 0) row_ptr[n_nodes] = n_edges;
    __syncthreads();
    cur[t] = excl;
    __syncthreads();
    for (int i = t; i < cnt; i += BSIZE) {
        int2 r = inter[base + i];
        int dlo = r.x & (BSIZE - 1);
        int p = atomicAdd(&cur[dlo], 1);
        float wf = __int_as_float(r.y);
        uint wq = (uint)(wf * 32768.0f);
        if (wq > 32767u) wq = 32767u;
        edges[base + p] = ((uint)(r.x >> BSHIFT) << 15) | wq;
    }
}

// ---------- convert: f32 features -> bf16, vectorized ----------
__global__ void cvt_bf16(const float* __restrict__ in, ushort* __restrict__ out, int n4) {
    int i = blockIdx.x * blockDim.x + threadIdx.x;
    int stride = gridDim.x * blockDim.x;
    for (; i < n4; i += stride) {
        float4 v = ((const float4*)in)[i];
        ushort4 o;
        o.x = f2bf(v.x); o.y = f2bf(v.y); o.z = f2bf(v.z); o.w = f2bf(v.w);
        ((ushort4*)out)[i] = o;
    }
}

// ---------- gather hop: one wave per NPW consecutive nodes; lane = feature ----------
// Long waves amortize the row_ptr/startup latency chain and keep 8 independent
// row loads in flight for ~90% of the wave lifetime (MLP fix, see R8 evidence).
template <bool OUT_BF16>
__global__ __launch_bounds__(256) void gather_hop(
        const ushort* __restrict__ h, const uint* __restrict__ edges,
        const int* __restrict__ row_ptr, void* __restrict__ out_v, int n_nodes) {
    int wv = blockIdx.x * 4 + (threadIdx.x >> 6);
    int n0 = __builtin_amdgcn_readfirstlane(wv * NPW);
    if (n0 >= n_nodes) return;
    int f = threadIdx.x & 63;

    int rp[NPW + 1];
    #pragma unroll
    for (int i = 0; i <= NPW; ++i)
        rp[i] = row_ptr[min(n0 + i, n_nodes)];      // uniform -> s_load

    #pragma unroll
    for (int ni = 0; ni < NPW; ++ni) {
        int node = n0 + ni;
        if (node >= n_nodes) break;
        int beg = __builtin_amdgcn_readfirstlane(rp[ni]);
        int end = __builtin_amdgcn_readfirstlane(rp[ni + 1]);
        float acc = 0.0f;
        int j = beg;
        for (; j + 8 <= end; j += 8) {
            #pragma unroll
            for (int k = 0; k < 8; ++k) {
                uint ev = edges[j + k];             // uniform -> scalar load
                acc += wq2f(ev) * bf2f(h[((size_t)(ev >> 15) << 6) + f]);
            }
        }
        for (; j < end; ++j) {
            uint ev = edges[j];
            acc += wq2f(ev) * bf2f(h[((size_t)(ev >> 15) << 6) + f]);
        }
        size_t o = ((size_t)node << 6) + f;
        if (OUT_BF16) ((ushort*)out_v)[o] = f2bf(acc);
        else          ((float*)out_v)[o]  = acc;
    }
}

extern "C" void kernel_launch(void* const* d_in, const int* in_sizes, int n_in,
                              void* d_out, int out_size, void* d_ws, size_t ws_size,
                              hipStream_t stream) {
    const float* x   = (const float*)d_in[0];
    const float* ew  = (const float*)d_in[1];
    const int*   src = (const int*)d_in[2];
    const int*   dst = (const int*)d_in[3];
    float* out = (float*)d_out;

    const int n_nodes = in_sizes[0] / D_FEAT;   // 100000
    const int n_edges = in_sizes[1];            // 3200000
    const int nbuck   = (n_nodes + BSIZE - 1) >> BSHIFT;   // 196
    const int n_feat_total = n_nodes * D_FEAT;

    const size_t ed8_bytes = (size_t)n_edges * 8;          // 25.6 MB (inter)
    const size_t ed4_bytes = (size_t)n_edges * 4;          // 12.8 MB (packed edges)
    const size_t bf_bytes  = (size_t)n_feat_total * 2;     // 12.8 MB

    // workspace: [region0: inter(25.6MB) -> later x_bf(12.8)+buf1(12.8)]
    //            [edges 12.8MB][row_ptr][bcount][bbase][bcursor]
    char* ws = (char*)d_ws;
    int2*   inter  = (int2*)ws;
    ushort* x_bf   = (ushort*)ws;
    ushort* buf1   = (ushort*)(ws + bf_bytes);
    ws += (ed8_bytes > 2 * bf_bytes ? ed8_bytes : 2 * bf_bytes);
    uint* edges    = (uint*)ws;                 ws += ed4_bytes;
    int*  row_ptr  = (int*)ws;                  ws += (size_t)(n_nodes + 1) * 4;
    int*  bcount   = (int*)ws;                  ws += 256 * 4;
    int*  bbase    = (int*)ws;                  ws += 256 * 4;
    int*  bcursor  = (int*)ws;

    // --- build dst-sorted CSR (bucketed counting sort); uses inter ---
    hipMemsetAsync(bcount, 0, 256 * 4, stream);
    bucket_hist<<<512, 256, 0, stream>>>(dst, bcount, n_edges);
    bucket_scan<<<1, 256, 0, stream>>>(bcount, bbase, bcursor);
    partition_kernel<<<(n_edges + CHUNK - 1) / CHUNK, 256, 0, stream>>>(
        src, dst, ew, bcursor, inter, n_edges);
    finalize_kernel<<<nbuck, BSIZE, 0, stream>>>(
        inter, bbase, bcount, edges, row_ptr, n_nodes, n_edges);

    // --- convert x to bf16 (inter region now free) ---
    cvt_bf16<<<1024, 256, 0, stream>>>(x, x_bf, n_feat_total / 4);

    // --- 3 gather hops: x_bf -> buf1 -> x_bf -> out(f32) ---
    const int waves = (n_nodes + NPW - 1) / NPW;
    const int grd = (waves + 3) / 4;
    gather_hop<true ><<<grd, 256, 0, stream>>>(x_bf, edges, row_ptr, buf1, n_nodes);
    gather_hop<true ><<<grd, 256, 0, stream>>>(buf1, edges, row_ptr, x_bf, n_nodes);
    gather_hop<false><<<grd, 256, 0, stream>>>(x_bf, edges, row_ptr, out,  n_nodes);
}